// Round 2
// baseline (1914.574 us; speedup 1.0000x reference)
//
#include <hip/hip_runtime.h>
#include <hip/hip_bf16.h>

// HAN forward, del-branch only (add-branch _group output is unused in the reference).
// ALL float tensors are float32 (per reference); ints int32; output f32 [4096,256].
// bf16 is used ONLY as MFMA input format (converted in-register, f32 accumulate).
//
// Pipeline:
//   1. gemm_h       : ha = x_add@W_add.T+b_add ; hd = x_del@W_del.T+b_del   (f32 out)
//   2. node_scores  : a_s/a_d per (node,head) for edge types ad, dd
//   3. edge_expsum  : per-edge exp(leaky_relu(a_s[src]+a_d[dst])), atomic denom per (dst,head)
//   4. edge_scatter : out[dst] += w * h_src  (f32 atomics, 64 lanes/edge)
//   5. kgemm_score  : score_m = sum_{n,f} q[f]*tanh(relu(out_m)@k_W.T+k_b)[n,f]
//   6. final_combine: softmax over 2 scores (mean /N), relu, blend, gather del_idx

typedef __attribute__((ext_vector_type(8))) __bf16 bf16x8;
typedef __attribute__((ext_vector_type(4))) float f32x4;

__device__ inline bf16x8 cvt8(f32x4 a, f32x4 b) {
    bf16x8 r;
    r[0] = (__bf16)a[0]; r[1] = (__bf16)a[1]; r[2] = (__bf16)a[2]; r[3] = (__bf16)a[3];
    r[4] = (__bf16)b[0]; r[5] = (__bf16)b[1]; r[6] = (__bf16)b[2]; r[7] = (__bf16)b[3];
    return r;
}

// ---------------- 1. h = X @ W^T + b : (M x 768) x (256 x 768)^T -> f32 [M,256] -----
// One wave computes 16 rows x 64 cols (4 n-tiles share the A fragment).
// mfma_f32_16x16x32_bf16: A[m=lane&15][k=quad*8+j]; B frag = W row n at k..k+7;
// C/D: col=lane&15, row=quad*4+reg (m89/m91-verified).
__global__ __launch_bounds__(256) void gemm_h(const float* __restrict__ X,
                                              const float* __restrict__ W,
                                              const float* __restrict__ bias,
                                              float* __restrict__ Hout) {
    int ng = threadIdx.x >> 6;     // n-group: 64 cols
    int mt = blockIdx.x;           // 0..1249
    int lane = threadIdx.x & 63;
    int row = lane & 15;
    int quad = lane >> 4;
    const float* xa = X + (size_t)(mt * 16 + row) * 768 + quad * 8;
    const float* wb = W + (size_t)(ng * 64 + row) * 768 + quad * 8;
    f32x4 acc[4] = {{0.f,0.f,0.f,0.f},{0.f,0.f,0.f,0.f},{0.f,0.f,0.f,0.f},{0.f,0.f,0.f,0.f}};
    for (int k = 0; k < 768; k += 32) {
        bf16x8 a = cvt8(*(const f32x4*)(xa + k), *(const f32x4*)(xa + k + 4));
#pragma unroll
        for (int t = 0; t < 4; ++t) {
            const float* bp = wb + (size_t)t * 16 * 768 + k;
            bf16x8 b = cvt8(*(const f32x4*)bp, *(const f32x4*)(bp + 4));
            acc[t] = __builtin_amdgcn_mfma_f32_16x16x32_bf16(a, b, acc[t], 0, 0, 0);
        }
    }
#pragma unroll
    for (int t = 0; t < 4; ++t) {
        int n = ng * 64 + t * 16 + row;
        float bn = bias[n];
#pragma unroll
        for (int r = 0; r < 4; ++r) {
            int m = mt * 16 + quad * 4 + r;
            Hout[(size_t)m * 256 + n] = acc[t][r] + bn;
        }
    }
}

// ---------------- 2. per-(node,head) attention scores -------------------------------
// One wave per node; lane covers 4 features; reduce within 32-lane halves (head each).
__global__ __launch_bounds__(256) void node_scores(const float* __restrict__ ha, const float* __restrict__ hd,
                                                   const float* __restrict__ w_ads, const float* __restrict__ w_add,
                                                   const float* __restrict__ w_dds, const float* __restrict__ w_ddd,
                                                   float* __restrict__ as_ad, float* __restrict__ ad_ad,
                                                   float* __restrict__ as_dd, float* __restrict__ ad_dd, int N) {
    int gid = blockIdx.x * 256 + threadIdx.x;
    int n = gid >> 6;
    if (n >= N) return;
    int lane = gid & 63;
    int f = lane * 4;
    float4 av = *(const float4*)(ha + (size_t)n * 256 + f);
    float4 dv = *(const float4*)(hd + (size_t)n * 256 + f);
    float4 w1 = *(const float4*)(w_ads + f);
    float4 w2 = *(const float4*)(w_add + f);
    float4 w3 = *(const float4*)(w_dds + f);
    float4 w4 = *(const float4*)(w_ddd + f);
    float p1 = av.x * w1.x + av.y * w1.y + av.z * w1.z + av.w * w1.w;
    float p2 = dv.x * w2.x + dv.y * w2.y + dv.z * w2.z + dv.w * w2.w;
    float p3 = dv.x * w3.x + dv.y * w3.y + dv.z * w3.z + dv.w * w3.w;
    float p4 = dv.x * w4.x + dv.y * w4.y + dv.z * w4.z + dv.w * w4.w;
#pragma unroll
    for (int off = 16; off >= 1; off >>= 1) {
        p1 += __shfl_down(p1, off, 32);
        p2 += __shfl_down(p2, off, 32);
        p3 += __shfl_down(p3, off, 32);
        p4 += __shfl_down(p4, off, 32);
    }
    if ((lane & 31) == 0) {
        int h = lane >> 5;
        as_ad[n * 2 + h] = p1;
        ad_ad[n * 2 + h] = p2;
        as_dd[n * 2 + h] = p3;
        ad_dd[n * 2 + h] = p4;
    }
}

// ---------------- 3. per-edge exp + denominator -------------------------------------
// Skip segment-max: |scores| small so exp is f32-safe; softmax is shift-invariant.
__global__ __launch_bounds__(256) void edge_expsum(const int* __restrict__ ei,
                                                   const float* __restrict__ a_src,
                                                   const float* __restrict__ a_dst,
                                                   float* __restrict__ ew, float* __restrict__ sum, int E) {
    int e = blockIdx.x * 256 + threadIdx.x;
    if (e >= E) return;
    int s = ei[e], d = ei[E + e];
#pragma unroll
    for (int h = 0; h < 2; ++h) {
        float v = a_src[s * 2 + h] + a_dst[d * 2 + h];
        v = v > 0.f ? v : 0.2f * v;     // leaky_relu(0.2)
        float ex = __expf(v);
        ew[(size_t)e * 2 + h] = ex;
        unsafeAtomicAdd(&sum[d * 2 + h], ex);
    }
}

// ---------------- 4. message scatter ------------------------------------------------
// 64 lanes per edge, 4 features/lane. Head = feature/128 -> lane>>5.
__global__ __launch_bounds__(256) void edge_scatter(const int* __restrict__ ei,
                                                    const float* __restrict__ ew,
                                                    const float* __restrict__ sum,
                                                    const float* __restrict__ hsrc,
                                                    float* __restrict__ out, int E) {
    int gid = blockIdx.x * 256 + threadIdx.x;
    int e = gid >> 6;
    if (e >= E) return;
    int lane = gid & 63;
    int s = ei[e], d = ei[E + e];
    int h = lane >> 5;
    float w = ew[(size_t)e * 2 + h] / (sum[d * 2 + h] + 1e-16f);
    int f = lane * 4;
    float4 xv = *(const float4*)(hsrc + (size_t)s * 256 + f);
    float* op = out + (size_t)d * 256 + f;
    unsafeAtomicAdd(op + 0, w * xv.x);
    unsafeAtomicAdd(op + 1, w * xv.y);
    unsafeAtomicAdd(op + 2, w * xv.z);
    unsafeAtomicAdd(op + 3, w * xv.w);
}

// ---------------- 5. semantic score: sum_{n,f} q[f]*tanh((relu(out)@kW.T + kb)[n,f]) -
// Wave computes 16 rows x 64 cols like gemm_h; relu+cvt at A load.
__global__ __launch_bounds__(256) void kgemm_score(const float* __restrict__ outm,
                                                   const float* __restrict__ kW,
                                                   const float* __restrict__ kb,
                                                   const float* __restrict__ qv,
                                                   float* __restrict__ score, int slot) {
    __shared__ float red[4];
    int ng = threadIdx.x >> 6;
    int mt = blockIdx.x;
    int lane = threadIdx.x & 63;
    int row = lane & 15;
    int quad = lane >> 4;
    const float* arow = outm + (size_t)(mt * 16 + row) * 256 + quad * 8;
    const float* brow = kW + (size_t)(ng * 64 + row) * 256 + quad * 8;
    f32x4 acc[4] = {{0.f,0.f,0.f,0.f},{0.f,0.f,0.f,0.f},{0.f,0.f,0.f,0.f},{0.f,0.f,0.f,0.f}};
    for (int k = 0; k < 256; k += 32) {
        f32x4 x0 = *(const f32x4*)(arow + k);
        f32x4 x1 = *(const f32x4*)(arow + k + 4);
#pragma unroll
        for (int j = 0; j < 4; ++j) {  // relu on A
            x0[j] = x0[j] > 0.f ? x0[j] : 0.f;
            x1[j] = x1[j] > 0.f ? x1[j] : 0.f;
        }
        bf16x8 a = cvt8(x0, x1);
#pragma unroll
        for (int t = 0; t < 4; ++t) {
            const float* bp = brow + (size_t)t * 16 * 256 + k;
            bf16x8 b = cvt8(*(const f32x4*)bp, *(const f32x4*)(bp + 4));
            acc[t] = __builtin_amdgcn_mfma_f32_16x16x32_bf16(a, b, acc[t], 0, 0, 0);
        }
    }
    float p = 0.f;
#pragma unroll
    for (int t = 0; t < 4; ++t) {
        int n = ng * 64 + t * 16 + row;
        float kbn = kb[n], qn = qv[n];
#pragma unroll
        for (int r = 0; r < 4; ++r) p += qn * tanhf(acc[t][r] + kbn);
    }
#pragma unroll
    for (int off = 32; off >= 1; off >>= 1) p += __shfl_down(p, off, 64);
    if (lane == 0) red[ng] = p;
    __syncthreads();
    if (threadIdx.x == 0) {
        unsafeAtomicAdd(&score[slot], red[0] + red[1] + red[2] + red[3]);
    }
}

// ---------------- 6. softmax over 2 metapath scores, blend, gather del_idx ----------
__global__ __launch_bounds__(256) void final_combine(const float* __restrict__ out_ad,
                                                     const float* __restrict__ out_dd,
                                                     const float* __restrict__ score,
                                                     const int* __restrict__ del_idx,
                                                     float* __restrict__ out) {
    int i = blockIdx.x;
    int f = threadIdx.x;
    int node = del_idx[i];
    float s0 = score[0] * (1.f / 20000.f);   // mean over nodes
    float s1 = score[1] * (1.f / 20000.f);
    float m = fmaxf(s0, s1);
    float e0 = __expf(s0 - m), e1 = __expf(s1 - m);
    float inv = 1.f / (e0 + e1);
    float a0 = e0 * inv, a1 = e1 * inv;
    float v0 = out_ad[(size_t)node * 256 + f]; v0 = v0 > 0.f ? v0 : 0.f;  // relu
    float v1 = out_dd[(size_t)node * 256 + f]; v1 = v1 > 0.f ? v1 : 0.f;
    out[(size_t)i * 256 + f] = a0 * v0 + a1 * v1;
}

extern "C" void kernel_launch(void* const* d_in, const int* in_sizes, int n_in,
                              void* d_out, int out_size, void* d_ws, size_t ws_size,
                              hipStream_t stream) {
    const float* x_add    = (const float*)d_in[0];
    const float* x_del    = (const float*)d_in[1];
    const float* W_add    = (const float*)d_in[2];
    const float* b_add    = (const float*)d_in[3];
    const float* W_del    = (const float*)d_in[4];
    const float* b_del    = (const float*)d_in[5];
    const float* att_ad_s = (const float*)d_in[6];
    const float* att_ad_d = (const float*)d_in[7];
    // d_in[8..11] = att_da_*/att_aa_* : unused (add-branch output is discarded)
    const float* att_dd_s = (const float*)d_in[12];
    const float* att_dd_d = (const float*)d_in[13];
    const float* k_W      = (const float*)d_in[14];
    const float* k_b      = (const float*)d_in[15];
    const float* q        = (const float*)d_in[16];
    const int* ei_ad      = (const int*)d_in[17];
    // d_in[18],[19] = ei_da, ei_aa : unused
    const int* ei_dd      = (const int*)d_in[20];
    const int* del_idx    = (const int*)d_in[21];
    float* out = (float*)d_out;

    const int N = 20000, E = 200000;
    char* ws = (char*)d_ws;
    size_t o = 0;
    float* out_ad = (float*)(ws + o); o += (size_t)N * 256 * 4;   // 20.48 MB
    float* out_dd = (float*)(ws + o); o += (size_t)N * 256 * 4;   // 20.48 MB
    float* sum_ad = (float*)(ws + o); o += (size_t)N * 2 * 4;
    float* sum_dd = (float*)(ws + o); o += (size_t)N * 2 * 4;
    float* score  = (float*)(ws + o); o += 256;
    size_t zero_bytes = o;                                        // ~41.3 MB zeroed
    float* ha    = (float*)(ws + o); o += (size_t)N * 256 * 4;    // 20.48 MB
    float* hd    = (float*)(ws + o); o += (size_t)N * 256 * 4;    // 20.48 MB
    float* as_ad = (float*)(ws + o); o += (size_t)N * 2 * 4;
    float* ad_ad = (float*)(ws + o); o += (size_t)N * 2 * 4;
    float* as_dd = (float*)(ws + o); o += (size_t)N * 2 * 4;
    float* ad_dd = (float*)(ws + o); o += (size_t)N * 2 * 4;
    float* ew_ad = (float*)(ws + o); o += (size_t)E * 2 * 4;
    float* ew_dd = (float*)(ws + o); o += (size_t)E * 2 * 4;      // total ~86 MB

    hipMemsetAsync(d_ws, 0, zero_bytes, stream);

    gemm_h<<<1250, 256, 0, stream>>>(x_add, W_add, b_add, ha);
    gemm_h<<<1250, 256, 0, stream>>>(x_del, W_del, b_del, hd);
    node_scores<<<5000, 256, 0, stream>>>(ha, hd, att_ad_s, att_ad_d, att_dd_s, att_dd_d,
                                          as_ad, ad_ad, as_dd, ad_dd, N);
    edge_expsum<<<(E + 255) / 256, 256, 0, stream>>>(ei_ad, as_ad, ad_ad, ew_ad, sum_ad, E);
    edge_expsum<<<(E + 255) / 256, 256, 0, stream>>>(ei_dd, as_dd, ad_dd, ew_dd, sum_dd, E);
    edge_scatter<<<E / 4, 256, 0, stream>>>(ei_ad, ew_ad, sum_ad, ha, out_ad, E);
    edge_scatter<<<E / 4, 256, 0, stream>>>(ei_dd, ew_dd, sum_dd, hd, out_dd, E);
    kgemm_score<<<1250, 256, 0, stream>>>(out_ad, k_W, k_b, q, score, 0);
    kgemm_score<<<1250, 256, 0, stream>>>(out_dd, k_W, k_b, q, score, 1);
    final_combine<<<4096, 256, 0, stream>>>(out_ad, out_dd, score, del_idx, out);
}

// Round 3
// 687.531 us; speedup vs baseline: 2.7847x; 2.7847x over previous
//
#include <hip/hip_runtime.h>
#include <hip/hip_bf16.h>

// HAN forward, del-branch only (add-branch _group output is unused in the reference).
// ALL float tensors are float32; ints int32; output f32 [4096,256].
// bf16 used ONLY as MFMA input format (in-register cvt, f32 accumulate).
//
// R3 change: atomic edge_scatter (819 MB HBM write-through per dispatch, 670 us)
// replaced by device-built CSR + one-wave-per-dst gather (each output written once).
//   1. gemm_h      : ha/hd = x@W.T+b (MFMA)
//   2. node_scores : per-(node,head) a_s/a_d dot products
//   3. count/scan/fill : CSR by dst for ei_ad, ei_dd
//   4. edge_gather : out[d] = (sum_e ex_e * h[src_e]) / (sum_e ex_e + 1e-16)
//   5. kgemm_score : score_m = sum q*tanh(relu(out_m)@kW.T+kb)
//   6. final_combine: 2-way softmax blend + del_idx gather

typedef __attribute__((ext_vector_type(8))) __bf16 bf16x8;
typedef __attribute__((ext_vector_type(4))) float f32x4;

__device__ inline bf16x8 cvt8(f32x4 a, f32x4 b) {
    bf16x8 r;
    r[0] = (__bf16)a[0]; r[1] = (__bf16)a[1]; r[2] = (__bf16)a[2]; r[3] = (__bf16)a[3];
    r[4] = (__bf16)b[0]; r[5] = (__bf16)b[1]; r[6] = (__bf16)b[2]; r[7] = (__bf16)b[3];
    return r;
}

// ---------------- 1. h = X @ W^T + b : (20000 x 768) x (256 x 768)^T -> f32 --------
__global__ __launch_bounds__(256) void gemm_h(const float* __restrict__ X,
                                              const float* __restrict__ W,
                                              const float* __restrict__ bias,
                                              float* __restrict__ Hout) {
    int ng = threadIdx.x >> 6;     // 64-col group
    int mt = blockIdx.x;           // 16-row tile
    int lane = threadIdx.x & 63;
    int row = lane & 15;
    int quad = lane >> 4;
    const float* xa = X + (size_t)(mt * 16 + row) * 768 + quad * 8;
    const float* wb = W + (size_t)(ng * 64 + row) * 768 + quad * 8;
    f32x4 acc[4] = {{0.f,0.f,0.f,0.f},{0.f,0.f,0.f,0.f},{0.f,0.f,0.f,0.f},{0.f,0.f,0.f,0.f}};
    for (int k = 0; k < 768; k += 32) {
        bf16x8 a = cvt8(*(const f32x4*)(xa + k), *(const f32x4*)(xa + k + 4));
#pragma unroll
        for (int t = 0; t < 4; ++t) {
            const float* bp = wb + (size_t)t * 16 * 768 + k;
            bf16x8 b = cvt8(*(const f32x4*)bp, *(const f32x4*)(bp + 4));
            acc[t] = __builtin_amdgcn_mfma_f32_16x16x32_bf16(a, b, acc[t], 0, 0, 0);
        }
    }
#pragma unroll
    for (int t = 0; t < 4; ++t) {
        int n = ng * 64 + t * 16 + row;
        float bn = bias[n];
#pragma unroll
        for (int r = 0; r < 4; ++r) {
            int m = mt * 16 + quad * 4 + r;
            Hout[(size_t)m * 256 + n] = acc[t][r] + bn;
        }
    }
}

// ---------------- 2. per-(node,head) attention scores ------------------------------
__global__ __launch_bounds__(256) void node_scores(const float* __restrict__ ha, const float* __restrict__ hd,
                                                   const float* __restrict__ w_ads, const float* __restrict__ w_add,
                                                   const float* __restrict__ w_dds, const float* __restrict__ w_ddd,
                                                   float* __restrict__ as_ad, float* __restrict__ ad_ad,
                                                   float* __restrict__ as_dd, float* __restrict__ ad_dd, int N) {
    int gid = blockIdx.x * 256 + threadIdx.x;
    int n = gid >> 6;
    if (n >= N) return;
    int lane = gid & 63;
    int f = lane * 4;
    float4 av = *(const float4*)(ha + (size_t)n * 256 + f);
    float4 dv = *(const float4*)(hd + (size_t)n * 256 + f);
    float4 w1 = *(const float4*)(w_ads + f);
    float4 w2 = *(const float4*)(w_add + f);
    float4 w3 = *(const float4*)(w_dds + f);
    float4 w4 = *(const float4*)(w_ddd + f);
    float p1 = av.x * w1.x + av.y * w1.y + av.z * w1.z + av.w * w1.w;
    float p2 = dv.x * w2.x + dv.y * w2.y + dv.z * w2.z + dv.w * w2.w;
    float p3 = dv.x * w3.x + dv.y * w3.y + dv.z * w3.z + dv.w * w3.w;
    float p4 = dv.x * w4.x + dv.y * w4.y + dv.z * w4.z + dv.w * w4.w;
#pragma unroll
    for (int off = 16; off >= 1; off >>= 1) {
        p1 += __shfl_down(p1, off, 32);
        p2 += __shfl_down(p2, off, 32);
        p3 += __shfl_down(p3, off, 32);
        p4 += __shfl_down(p4, off, 32);
    }
    if ((lane & 31) == 0) {
        int h = lane >> 5;
        as_ad[n * 2 + h] = p1;
        ad_ad[n * 2 + h] = p2;
        as_dd[n * 2 + h] = p3;
        ad_dd[n * 2 + h] = p4;
    }
}

// ---------------- 3a. degree histogram ---------------------------------------------
__global__ __launch_bounds__(256) void count_edges(const int* __restrict__ ei, int* __restrict__ cnt, int E) {
    int e = blockIdx.x * 256 + threadIdx.x;
    if (e >= E) return;
    atomicAdd(&cnt[ei[E + e]], 1);
}

// ---------------- 3b. exclusive scan of two count arrays (block 0 -> A, 1 -> B) ----
__global__ __launch_bounds__(1024) void scan_two(const int* __restrict__ cntA, int* __restrict__ offA,
                                                 const int* __restrict__ cntB, int* __restrict__ offB, int n) {
    const int* cnt = blockIdx.x ? cntB : cntA;
    int* off = blockIdx.x ? offB : offA;
    __shared__ int smem[1024];
    __shared__ int carry_s;
    int tid = threadIdx.x;
    if (tid == 0) carry_s = 0;
    __syncthreads();
    for (int base = 0; base < n; base += 1024) {
        int i = base + tid;
        int v = (i < n) ? cnt[i] : 0;
        smem[tid] = v;
        __syncthreads();
#pragma unroll
        for (int d = 1; d < 1024; d <<= 1) {
            int t = (tid >= d) ? smem[tid - d] : 0;
            __syncthreads();
            smem[tid] += t;
            __syncthreads();
        }
        int incl = smem[tid];
        int carry = carry_s;
        if (i < n) off[i] = carry + incl - v;   // exclusive
        __syncthreads();
        if (tid == 1023) carry_s = carry + smem[1023];
        __syncthreads();
    }
    if (tid == 0) off[n] = carry_s;
}

// ---------------- 3c. fill CSR src lists -------------------------------------------
__global__ __launch_bounds__(256) void fill_csr(const int* __restrict__ ei, const int* __restrict__ off,
                                                int* __restrict__ cursor, int* __restrict__ srcs, int E) {
    int e = blockIdx.x * 256 + threadIdx.x;
    if (e >= E) return;
    int s = ei[e], d = ei[E + e];
    int slot = off[d] + atomicAdd(&cursor[d], 1);
    srcs[slot] = s;
}

// ---------------- 4. gather: one wave per dst node ---------------------------------
// out[d,f] = (sum_e ex_e * h[src_e, f]) / (sum_e ex_e + 1e-16)
// ex_e = exp(leaky_relu(a_s[src]+a_d[dst])); head = f/128 = lane>>5.
__global__ __launch_bounds__(256) void edge_gather(const int* __restrict__ off,
                                                   const int* __restrict__ srcs,
                                                   const float* __restrict__ a_src,
                                                   const float* __restrict__ a_dst,
                                                   const float* __restrict__ h,
                                                   float* __restrict__ out, int N) {
    int gid = blockIdx.x * 256 + threadIdx.x;
    int d = gid >> 6;
    if (d >= N) return;
    int lane = gid & 63;
    int hh = lane >> 5;
    int f = lane * 4;
    float ad0 = a_dst[d * 2 + hh];
    int beg = off[d], end = off[d + 1];
    float4 acc = {0.f, 0.f, 0.f, 0.f};
    float S = 0.f;
    for (int p = beg; p < end; ++p) {
        int s = srcs[p];
        float v = a_src[s * 2 + hh] + ad0;
        v = v > 0.f ? v : 0.2f * v;           // leaky_relu(0.2)
        float ex = __expf(v);
        S += ex;
        float4 xv = *(const float4*)(h + (size_t)s * 256 + f);
        acc.x += ex * xv.x;
        acc.y += ex * xv.y;
        acc.z += ex * xv.z;
        acc.w += ex * xv.w;
    }
    float inv = 1.f / (S + 1e-16f);
    float4 o = {acc.x * inv, acc.y * inv, acc.z * inv, acc.w * inv};
    *(float4*)(out + (size_t)d * 256 + f) = o;
}

// ---------------- 5. semantic score ------------------------------------------------
__global__ __launch_bounds__(256) void kgemm_score(const float* __restrict__ outm,
                                                   const float* __restrict__ kW,
                                                   const float* __restrict__ kb,
                                                   const float* __restrict__ qv,
                                                   float* __restrict__ score, int slot) {
    __shared__ float red[4];
    int ng = threadIdx.x >> 6;
    int mt = blockIdx.x;
    int lane = threadIdx.x & 63;
    int row = lane & 15;
    int quad = lane >> 4;
    const float* arow = outm + (size_t)(mt * 16 + row) * 256 + quad * 8;
    const float* brow = kW + (size_t)(ng * 64 + row) * 256 + quad * 8;
    f32x4 acc[4] = {{0.f,0.f,0.f,0.f},{0.f,0.f,0.f,0.f},{0.f,0.f,0.f,0.f},{0.f,0.f,0.f,0.f}};
    for (int k = 0; k < 256; k += 32) {
        f32x4 x0 = *(const f32x4*)(arow + k);
        f32x4 x1 = *(const f32x4*)(arow + k + 4);
#pragma unroll
        for (int j = 0; j < 4; ++j) {
            x0[j] = x0[j] > 0.f ? x0[j] : 0.f;
            x1[j] = x1[j] > 0.f ? x1[j] : 0.f;
        }
        bf16x8 a = cvt8(x0, x1);
#pragma unroll
        for (int t = 0; t < 4; ++t) {
            const float* bp = brow + (size_t)t * 16 * 256 + k;
            bf16x8 b = cvt8(*(const f32x4*)bp, *(const f32x4*)(bp + 4));
            acc[t] = __builtin_amdgcn_mfma_f32_16x16x32_bf16(a, b, acc[t], 0, 0, 0);
        }
    }
    float p = 0.f;
#pragma unroll
    for (int t = 0; t < 4; ++t) {
        int n = ng * 64 + t * 16 + row;
        float kbn = kb[n], qn = qv[n];
#pragma unroll
        for (int r = 0; r < 4; ++r) p += qn * tanhf(acc[t][r] + kbn);
    }
#pragma unroll
    for (int off = 32; off >= 1; off >>= 1) p += __shfl_down(p, off, 64);
    if (lane == 0) red[ng] = p;
    __syncthreads();
    if (threadIdx.x == 0) {
        unsafeAtomicAdd(&score[slot], red[0] + red[1] + red[2] + red[3]);
    }
}

// ---------------- 6. softmax over 2 metapath scores, blend, gather del_idx ----------
__global__ __launch_bounds__(256) void final_combine(const float* __restrict__ out_ad,
                                                     const float* __restrict__ out_dd,
                                                     const float* __restrict__ score,
                                                     const int* __restrict__ del_idx,
                                                     float* __restrict__ out) {
    int i = blockIdx.x;
    int f = threadIdx.x;
    int node = del_idx[i];
    float s0 = score[0] * (1.f / 20000.f);
    float s1 = score[1] * (1.f / 20000.f);
    float m = fmaxf(s0, s1);
    float e0 = __expf(s0 - m), e1 = __expf(s1 - m);
    float inv = 1.f / (e0 + e1);
    float a0 = e0 * inv, a1 = e1 * inv;
    float v0 = out_ad[(size_t)node * 256 + f]; v0 = v0 > 0.f ? v0 : 0.f;
    float v1 = out_dd[(size_t)node * 256 + f]; v1 = v1 > 0.f ? v1 : 0.f;
    out[(size_t)i * 256 + f] = a0 * v0 + a1 * v1;
}

extern "C" void kernel_launch(void* const* d_in, const int* in_sizes, int n_in,
                              void* d_out, int out_size, void* d_ws, size_t ws_size,
                              hipStream_t stream) {
    const float* x_add    = (const float*)d_in[0];
    const float* x_del    = (const float*)d_in[1];
    const float* W_add    = (const float*)d_in[2];
    const float* b_add    = (const float*)d_in[3];
    const float* W_del    = (const float*)d_in[4];
    const float* b_del    = (const float*)d_in[5];
    const float* att_ad_s = (const float*)d_in[6];
    const float* att_ad_d = (const float*)d_in[7];
    const float* att_dd_s = (const float*)d_in[12];
    const float* att_dd_d = (const float*)d_in[13];
    const float* k_W      = (const float*)d_in[14];
    const float* k_b      = (const float*)d_in[15];
    const float* q        = (const float*)d_in[16];
    const int* ei_ad      = (const int*)d_in[17];
    const int* ei_dd      = (const int*)d_in[20];
    const int* del_idx    = (const int*)d_in[21];
    float* out = (float*)d_out;

    const int N = 20000, E = 200000;
    char* ws = (char*)d_ws;
    size_t o = 0;
    // ---- zeroed region (memset below) ----
    int* cnt_ad = (int*)(ws + o); o += (size_t)N * 4;
    int* cur_ad = (int*)(ws + o); o += (size_t)N * 4;
    int* cnt_dd = (int*)(ws + o); o += (size_t)N * 4;
    int* cur_dd = (int*)(ws + o); o += (size_t)N * 4;
    float* score = (float*)(ws + o); o += 256;
    size_t zero_bytes = o;                                        // ~320 KB
    // ---- written-once region ----
    int* off_ad = (int*)(ws + o); o += (size_t)(N + 1) * 4;
    int* off_dd = (int*)(ws + o); o += (size_t)(N + 1) * 4;
    int* srcs_ad = (int*)(ws + o); o += (size_t)E * 4;
    int* srcs_dd = (int*)(ws + o); o += (size_t)E * 4;
    float* out_ad = (float*)(ws + o); o += (size_t)N * 256 * 4;
    float* out_dd = (float*)(ws + o); o += (size_t)N * 256 * 4;
    float* ha    = (float*)(ws + o); o += (size_t)N * 256 * 4;
    float* hd    = (float*)(ws + o); o += (size_t)N * 256 * 4;
    float* as_ad = (float*)(ws + o); o += (size_t)N * 2 * 4;
    float* ad_ad = (float*)(ws + o); o += (size_t)N * 2 * 4;
    float* as_dd = (float*)(ws + o); o += (size_t)N * 2 * 4;
    float* ad_dd = (float*)(ws + o); o += (size_t)N * 2 * 4;      // total ~85 MB

    hipMemsetAsync(d_ws, 0, zero_bytes, stream);

    // CSR build (independent of GEMMs, but stream-ordered anyway)
    count_edges<<<(E + 255) / 256, 256, 0, stream>>>(ei_ad, cnt_ad, E);
    count_edges<<<(E + 255) / 256, 256, 0, stream>>>(ei_dd, cnt_dd, E);
    scan_two<<<2, 1024, 0, stream>>>(cnt_ad, off_ad, cnt_dd, off_dd, N);
    fill_csr<<<(E + 255) / 256, 256, 0, stream>>>(ei_ad, off_ad, cur_ad, srcs_ad, E);
    fill_csr<<<(E + 255) / 256, 256, 0, stream>>>(ei_dd, off_dd, cur_dd, srcs_dd, E);

    gemm_h<<<1250, 256, 0, stream>>>(x_add, W_add, b_add, ha);
    gemm_h<<<1250, 256, 0, stream>>>(x_del, W_del, b_del, hd);
    node_scores<<<5000, 256, 0, stream>>>(ha, hd, att_ad_s, att_ad_d, att_dd_s, att_dd_d,
                                          as_ad, ad_ad, as_dd, ad_dd, N);

    edge_gather<<<5000, 256, 0, stream>>>(off_ad, srcs_ad, as_ad, ad_ad, ha, out_ad, N);
    edge_gather<<<5000, 256, 0, stream>>>(off_dd, srcs_dd, as_dd, ad_dd, hd, out_dd, N);

    kgemm_score<<<1250, 256, 0, stream>>>(out_ad, k_W, k_b, q, score, 0);
    kgemm_score<<<1250, 256, 0, stream>>>(out_dd, k_W, k_b, q, score, 1);
    final_combine<<<4096, 256, 0, stream>>>(out_ad, out_dd, score, del_idx, out);
}

// Round 4
// 502.579 us; speedup vs baseline: 3.8095x; 1.3680x over previous
//
#include <hip/hip_runtime.h>
#include <hip/hip_bf16.h>

// HAN forward, del-branch only (add-branch _group output is unused in the reference).
// Inputs f32 / int32; output f32 [4096,256]. h stored bf16 (MFMA-native, halves traffic).
//
// R4 change: gemm_h was latency-bound (MfmaUtil 2%, VALUBusy 5%, occ 37%) — per-wave
// direct-from-L2 loads with no reuse. Now LDS-tiled BM=64 BN=128 BK=32 (f32->bf16 cvt
// folded into staging), padded LDS stride 40 elems (conflict-free b128), h output bf16.

typedef unsigned short u16;
typedef __attribute__((ext_vector_type(8))) __bf16 bf16x8;
typedef __attribute__((ext_vector_type(4))) float f32x4;

__device__ inline float bf2f(u16 u) {
    union { unsigned int i; float f; } c; c.i = ((unsigned int)u) << 16; return c.f;
}
__device__ inline u16 f2bf(float f) {  // round-to-nearest-even
    union { float f; unsigned int i; } c; c.f = f;
    return (u16)((c.i + 0x7fffu + ((c.i >> 16) & 1u)) >> 16);
}
__device__ inline bf16x8 cvt8(f32x4 a, f32x4 b) {
    bf16x8 r;
    r[0] = (__bf16)a[0]; r[1] = (__bf16)a[1]; r[2] = (__bf16)a[2]; r[3] = (__bf16)a[3];
    r[4] = (__bf16)b[0]; r[5] = (__bf16)b[1]; r[6] = (__bf16)b[2]; r[7] = (__bf16)b[3];
    return r;
}

// ---------------- 1. h = X @ W^T + b : [M x 768] x [256 x 768]^T -> bf16 [M,256] ----
// BM=64 BN=128 BK=32, 256 thr = 4 waves in 2x2; wave computes 32x64 (2x4 MFMA frags).
// LDS rows padded to 40 elems (80 B = 5*16: b128-aligned, bank-conflict-free).
#define SA 40
__global__ __launch_bounds__(256) void gemm_h(const float* __restrict__ X,
                                              const float* __restrict__ W,
                                              const float* __restrict__ bias,
                                              u16* __restrict__ H, int M) {
    __shared__ u16 As[64 * SA];
    __shared__ u16 Bs[128 * SA];
    int bm = blockIdx.x >> 1, bn = blockIdx.x & 1;
    int tid = threadIdx.x;
    int w = tid >> 6, lane = tid & 63;
    int wm = w & 1, wn = w >> 1;
    int row16 = lane & 15, quad = lane >> 4;

    // staging source/dest (thread i: A chunk i, B chunks i and i+256; chunk = 8 elems)
    int ar = bm * 64 + (tid >> 2); if (ar > M - 1) ar = M - 1;
    const float* ag = X + (size_t)ar * 768 + (tid & 3) * 8;
    u16* asw = As + (tid >> 2) * SA + (tid & 3) * 8;
    const float* bg0 = W + (size_t)(bn * 128 + (tid >> 2)) * 768 + (tid & 3) * 8;
    u16* bsw0 = Bs + (tid >> 2) * SA + (tid & 3) * 8;
    int j1 = tid + 256;
    const float* bg1 = W + (size_t)(bn * 128 + (j1 >> 2)) * 768 + (j1 & 3) * 8;
    u16* bsw1 = Bs + (j1 >> 2) * SA + (j1 & 3) * 8;

    // compute-side LDS addresses
    const u16* ard0 = As + (wm * 32 + row16) * SA + quad * 8;
    const u16* ard1 = As + (wm * 32 + 16 + row16) * SA + quad * 8;
    const u16* brd = Bs + (wn * 64 + row16) * SA + quad * 8;

    f32x4 acc[2][4] = {};
    for (int k = 0; k < 768; k += 32) {
        bf16x8 va  = cvt8(*(const f32x4*)(ag + k),  *(const f32x4*)(ag + k + 4));
        bf16x8 vb0 = cvt8(*(const f32x4*)(bg0 + k), *(const f32x4*)(bg0 + k + 4));
        bf16x8 vb1 = cvt8(*(const f32x4*)(bg1 + k), *(const f32x4*)(bg1 + k + 4));
        __syncthreads();
        *(bf16x8*)asw = va;
        *(bf16x8*)bsw0 = vb0;
        *(bf16x8*)bsw1 = vb1;
        __syncthreads();
        bf16x8 af0 = *(const bf16x8*)ard0;
        bf16x8 af1 = *(const bf16x8*)ard1;
#pragma unroll
        for (int ni = 0; ni < 4; ++ni) {
            bf16x8 bf = *(const bf16x8*)(brd + ni * 16 * SA);
            acc[0][ni] = __builtin_amdgcn_mfma_f32_16x16x32_bf16(af0, bf, acc[0][ni], 0, 0, 0);
            acc[1][ni] = __builtin_amdgcn_mfma_f32_16x16x32_bf16(af1, bf, acc[1][ni], 0, 0, 0);
        }
    }
#pragma unroll
    for (int ni = 0; ni < 4; ++ni) {
        int gcol = bn * 128 + wn * 64 + ni * 16 + row16;
        float bv = bias[gcol];
#pragma unroll
        for (int mi = 0; mi < 2; ++mi) {
#pragma unroll
            for (int r = 0; r < 4; ++r) {
                int grow = bm * 64 + wm * 32 + mi * 16 + quad * 4 + r;
                if (grow < M) H[(size_t)grow * 256 + gcol] = f2bf(acc[mi][ni][r] + bv);
            }
        }
    }
}

// ---------------- 2. per-(node,head) attention scores (h is bf16 now) ---------------
__global__ __launch_bounds__(256) void node_scores(const u16* __restrict__ ha, const u16* __restrict__ hd,
                                                   const float* __restrict__ w_ads, const float* __restrict__ w_add,
                                                   const float* __restrict__ w_dds, const float* __restrict__ w_ddd,
                                                   float* __restrict__ as_ad, float* __restrict__ ad_ad,
                                                   float* __restrict__ as_dd, float* __restrict__ ad_dd, int N) {
    int gid = blockIdx.x * 256 + threadIdx.x;
    int n = gid >> 6;
    if (n >= N) return;
    int lane = gid & 63;
    int f = lane * 4;
    ushort4 av = *(const ushort4*)(ha + (size_t)n * 256 + f);
    ushort4 dv = *(const ushort4*)(hd + (size_t)n * 256 + f);
    float4 w1 = *(const float4*)(w_ads + f);
    float4 w2 = *(const float4*)(w_add + f);
    float4 w3 = *(const float4*)(w_dds + f);
    float4 w4 = *(const float4*)(w_ddd + f);
    float a0 = bf2f(av.x), a1 = bf2f(av.y), a2 = bf2f(av.z), a3 = bf2f(av.w);
    float d0 = bf2f(dv.x), d1 = bf2f(dv.y), d2 = bf2f(dv.z), d3 = bf2f(dv.w);
    float p1 = a0 * w1.x + a1 * w1.y + a2 * w1.z + a3 * w1.w;
    float p2 = d0 * w2.x + d1 * w2.y + d2 * w2.z + d3 * w2.w;
    float p3 = d0 * w3.x + d1 * w3.y + d2 * w3.z + d3 * w3.w;
    float p4 = d0 * w4.x + d1 * w4.y + d2 * w4.z + d3 * w4.w;
#pragma unroll
    for (int off = 16; off >= 1; off >>= 1) {
        p1 += __shfl_down(p1, off, 32);
        p2 += __shfl_down(p2, off, 32);
        p3 += __shfl_down(p3, off, 32);
        p4 += __shfl_down(p4, off, 32);
    }
    if ((lane & 31) == 0) {
        int h = lane >> 5;
        as_ad[n * 2 + h] = p1;
        ad_ad[n * 2 + h] = p2;
        as_dd[n * 2 + h] = p3;
        ad_dd[n * 2 + h] = p4;
    }
}

// ---------------- 3a. degree histogram ----------------------------------------------
__global__ __launch_bounds__(256) void count_edges(const int* __restrict__ ei, int* __restrict__ cnt, int E) {
    int e = blockIdx.x * 256 + threadIdx.x;
    if (e >= E) return;
    atomicAdd(&cnt[ei[E + e]], 1);
}

// ---------------- 3b. exclusive scan of two count arrays ----------------------------
__global__ __launch_bounds__(1024) void scan_two(const int* __restrict__ cntA, int* __restrict__ offA,
                                                 const int* __restrict__ cntB, int* __restrict__ offB, int n) {
    const int* cnt = blockIdx.x ? cntB : cntA;
    int* off = blockIdx.x ? offB : offA;
    __shared__ int smem[1024];
    __shared__ int carry_s;
    int tid = threadIdx.x;
    if (tid == 0) carry_s = 0;
    __syncthreads();
    for (int base = 0; base < n; base += 1024) {
        int i = base + tid;
        int v = (i < n) ? cnt[i] : 0;
        smem[tid] = v;
        __syncthreads();
#pragma unroll
        for (int d = 1; d < 1024; d <<= 1) {
            int t = (tid >= d) ? smem[tid - d] : 0;
            __syncthreads();
            smem[tid] += t;
            __syncthreads();
        }
        int incl = smem[tid];
        int carry = carry_s;
        if (i < n) off[i] = carry + incl - v;   // exclusive
        __syncthreads();
        if (tid == 1023) carry_s = carry + smem[1023];
        __syncthreads();
    }
    if (tid == 0) off[n] = carry_s;
}

// ---------------- 3c. fill CSR src lists --------------------------------------------
__global__ __launch_bounds__(256) void fill_csr(const int* __restrict__ ei, const int* __restrict__ off,
                                                int* __restrict__ cursor, int* __restrict__ srcs, int E) {
    int e = blockIdx.x * 256 + threadIdx.x;
    if (e >= E) return;
    int s = ei[e], d = ei[E + e];
    int slot = off[d] + atomicAdd(&cursor[d], 1);
    srcs[slot] = s;
}

// ---------------- 4. gather: one wave per dst node (h bf16) -------------------------
__global__ __launch_bounds__(256) void edge_gather(const int* __restrict__ off,
                                                   const int* __restrict__ srcs,
                                                   const float* __restrict__ a_src,
                                                   const float* __restrict__ a_dst,
                                                   const u16* __restrict__ h,
                                                   float* __restrict__ out, int N) {
    int gid = blockIdx.x * 256 + threadIdx.x;
    int d = gid >> 6;
    if (d >= N) return;
    int lane = gid & 63;
    int hh = lane >> 5;
    int f = lane * 4;
    float ad0 = a_dst[d * 2 + hh];
    int beg = off[d], end = off[d + 1];
    float4 acc = {0.f, 0.f, 0.f, 0.f};
    float S = 0.f;
    for (int p = beg; p < end; ++p) {
        int s = srcs[p];
        float v = a_src[s * 2 + hh] + ad0;
        v = v > 0.f ? v : 0.2f * v;           // leaky_relu(0.2)
        float ex = __expf(v);
        S += ex;
        ushort4 xv = *(const ushort4*)(h + (size_t)s * 256 + f);
        acc.x += ex * bf2f(xv.x);
        acc.y += ex * bf2f(xv.y);
        acc.z += ex * bf2f(xv.z);
        acc.w += ex * bf2f(xv.w);
    }
    float inv = 1.f / (S + 1e-16f);
    float4 o = {acc.x * inv, acc.y * inv, acc.z * inv, acc.w * inv};
    *(float4*)(out + (size_t)d * 256 + f) = o;
}

// ---------------- 5. semantic score -------------------------------------------------
__global__ __launch_bounds__(256) void kgemm_score(const float* __restrict__ outm,
                                                   const float* __restrict__ kW,
                                                   const float* __restrict__ kb,
                                                   const float* __restrict__ qv,
                                                   float* __restrict__ score, int slot) {
    __shared__ float red[4];
    int ng = threadIdx.x >> 6;
    int mt = blockIdx.x;
    int lane = threadIdx.x & 63;
    int row = lane & 15;
    int quad = lane >> 4;
    const float* arow = outm + (size_t)(mt * 16 + row) * 256 + quad * 8;
    const float* brow = kW + (size_t)(ng * 64 + row) * 256 + quad * 8;
    f32x4 acc[4] = {{0.f,0.f,0.f,0.f},{0.f,0.f,0.f,0.f},{0.f,0.f,0.f,0.f},{0.f,0.f,0.f,0.f}};
    for (int k = 0; k < 256; k += 32) {
        f32x4 x0 = *(const f32x4*)(arow + k);
        f32x4 x1 = *(const f32x4*)(arow + k + 4);
#pragma unroll
        for (int j = 0; j < 4; ++j) {
            x0[j] = x0[j] > 0.f ? x0[j] : 0.f;
            x1[j] = x1[j] > 0.f ? x1[j] : 0.f;
        }
        bf16x8 a = cvt8(x0, x1);
#pragma unroll
        for (int t = 0; t < 4; ++t) {
            const float* bp = brow + (size_t)t * 16 * 256 + k;
            bf16x8 b = cvt8(*(const f32x4*)bp, *(const f32x4*)(bp + 4));
            acc[t] = __builtin_amdgcn_mfma_f32_16x16x32_bf16(a, b, acc[t], 0, 0, 0);
        }
    }
    float p = 0.f;
#pragma unroll
    for (int t = 0; t < 4; ++t) {
        int n = ng * 64 + t * 16 + row;
        float kbn = kb[n], qn = qv[n];
#pragma unroll
        for (int r = 0; r < 4; ++r) p += qn * tanhf(acc[t][r] + kbn);
    }
#pragma unroll
    for (int off = 32; off >= 1; off >>= 1) p += __shfl_down(p, off, 64);
    if (lane == 0) red[ng] = p;
    __syncthreads();
    if (threadIdx.x == 0) {
        unsafeAtomicAdd(&score[slot], red[0] + red[1] + red[2] + red[3]);
    }
}

// ---------------- 6. softmax over 2 metapath scores, blend, gather del_idx ----------
__global__ __launch_bounds__(256) void final_combine(const float* __restrict__ out_ad,
                                                     const float* __restrict__ out_dd,
                                                     const float* __restrict__ score,
                                                     const int* __restrict__ del_idx,
                                                     float* __restrict__ out) {
    int i = blockIdx.x;
    int f = threadIdx.x;
    int node = del_idx[i];
    float s0 = score[0] * (1.f / 20000.f);
    float s1 = score[1] * (1.f / 20000.f);
    float m = fmaxf(s0, s1);
    float e0 = __expf(s0 - m), e1 = __expf(s1 - m);
    float inv = 1.f / (e0 + e1);
    float a0 = e0 * inv, a1 = e1 * inv;
    float v0 = out_ad[(size_t)node * 256 + f]; v0 = v0 > 0.f ? v0 : 0.f;
    float v1 = out_dd[(size_t)node * 256 + f]; v1 = v1 > 0.f ? v1 : 0.f;
    out[(size_t)i * 256 + f] = a0 * v0 + a1 * v1;
}

extern "C" void kernel_launch(void* const* d_in, const int* in_sizes, int n_in,
                              void* d_out, int out_size, void* d_ws, size_t ws_size,
                              hipStream_t stream) {
    const float* x_add    = (const float*)d_in[0];
    const float* x_del    = (const float*)d_in[1];
    const float* W_add    = (const float*)d_in[2];
    const float* b_add    = (const float*)d_in[3];
    const float* W_del    = (const float*)d_in[4];
    const float* b_del    = (const float*)d_in[5];
    const float* att_ad_s = (const float*)d_in[6];
    const float* att_ad_d = (const float*)d_in[7];
    const float* att_dd_s = (const float*)d_in[12];
    const float* att_dd_d = (const float*)d_in[13];
    const float* k_W      = (const float*)d_in[14];
    const float* k_b      = (const float*)d_in[15];
    const float* q        = (const float*)d_in[16];
    const int* ei_ad      = (const int*)d_in[17];
    const int* ei_dd      = (const int*)d_in[20];
    const int* del_idx    = (const int*)d_in[21];
    float* out = (float*)d_out;

    const int N = 20000, E = 200000;
    char* ws = (char*)d_ws;
    size_t o = 0;
    // ---- zeroed region ----
    int* cnt_ad = (int*)(ws + o); o += (size_t)N * 4;
    int* cur_ad = (int*)(ws + o); o += (size_t)N * 4;
    int* cnt_dd = (int*)(ws + o); o += (size_t)N * 4;
    int* cur_dd = (int*)(ws + o); o += (size_t)N * 4;
    float* score = (float*)(ws + o); o += 256;
    size_t zero_bytes = o;                                        // ~320 KB
    // ---- written-once region ----
    int* off_ad = (int*)(ws + o); o += (size_t)(N + 1) * 4;
    int* off_dd = (int*)(ws + o); o += (size_t)(N + 1) * 4;
    int* srcs_ad = (int*)(ws + o); o += (size_t)E * 4;
    int* srcs_dd = (int*)(ws + o); o += (size_t)E * 4;
    float* out_ad = (float*)(ws + o); o += (size_t)N * 256 * 4;   // 20.48 MB
    float* out_dd = (float*)(ws + o); o += (size_t)N * 256 * 4;   // 20.48 MB
    u16* ha    = (u16*)(ws + o); o += (size_t)N * 256 * 2;        // 10.24 MB
    u16* hd    = (u16*)(ws + o); o += (size_t)N * 256 * 2;        // 10.24 MB
    float* as_ad = (float*)(ws + o); o += (size_t)N * 2 * 4;
    float* ad_ad = (float*)(ws + o); o += (size_t)N * 2 * 4;
    float* as_dd = (float*)(ws + o); o += (size_t)N * 2 * 4;
    float* ad_dd = (float*)(ws + o); o += (size_t)N * 2 * 4;      // total ~65 MB

    hipMemsetAsync(d_ws, 0, zero_bytes, stream);

    // CSR build
    count_edges<<<(E + 255) / 256, 256, 0, stream>>>(ei_ad, cnt_ad, E);
    count_edges<<<(E + 255) / 256, 256, 0, stream>>>(ei_dd, cnt_dd, E);
    scan_two<<<2, 1024, 0, stream>>>(cnt_ad, off_ad, cnt_dd, off_dd, N);
    fill_csr<<<(E + 255) / 256, 256, 0, stream>>>(ei_ad, off_ad, cur_ad, srcs_ad, E);
    fill_csr<<<(E + 255) / 256, 256, 0, stream>>>(ei_dd, off_dd, cur_dd, srcs_dd, E);

    // projections: 313 m-tiles (last partial) x 2 n-tiles
    gemm_h<<<626, 256, 0, stream>>>(x_add, W_add, b_add, ha, N);
    gemm_h<<<626, 256, 0, stream>>>(x_del, W_del, b_del, hd, N);
    node_scores<<<5000, 256, 0, stream>>>(ha, hd, att_ad_s, att_ad_d, att_dd_s, att_dd_d,
                                          as_ad, ad_ad, as_dd, ad_dd, N);

    edge_gather<<<5000, 256, 0, stream>>>(off_ad, srcs_ad, as_ad, ad_ad, ha, out_ad, N);
    edge_gather<<<5000, 256, 0, stream>>>(off_dd, srcs_dd, as_dd, ad_dd, hd, out_dd, N);

    kgemm_score<<<1250, 256, 0, stream>>>(out_ad, k_W, k_b, q, score, 0);
    kgemm_score<<<1250, 256, 0, stream>>>(out_dd, k_W, k_b, q, score, 1);
    final_combine<<<4096, 256, 0, stream>>>(out_ad, out_dd, score, del_idx, out);
}

// Round 5
// 449.041 us; speedup vs baseline: 4.2637x; 1.1192x over previous
//
#include <hip/hip_runtime.h>
#include <hip/hip_bf16.h>

// HAN forward, del-branch only (add-branch _group output is unused in the reference).
// Inputs f32 / int32; output f32 [4096,256]. h stored bf16.
//
// R5 change: kgemm_score was latency-bound (MfmaUtil 1.7%, VALUBusy 13%) — k_W
// re-streamed from L2 by all 1250 blocks with dependent loads. Now: 256 blocks
// (128 m-groups x 2 col-halves), k_W half staged to LDS bf16 once per block
// (66 KB, stride 264), ~10 m-tiles per block with ALL 16 A-loads issued up front
// per m-tile (1 latency round-trip), fast tanh via v_exp_f32.

typedef unsigned short u16;
typedef __attribute__((ext_vector_type(8))) __bf16 bf16x8;
typedef __attribute__((ext_vector_type(4))) float f32x4;

__device__ inline float bf2f(u16 u) {
    union { unsigned int i; float f; } c; c.i = ((unsigned int)u) << 16; return c.f;
}
__device__ inline u16 f2bf(float f) {  // round-to-nearest-even
    union { float f; unsigned int i; } c; c.f = f;
    return (u16)((c.i + 0x7fffu + ((c.i >> 16) & 1u)) >> 16);
}
__device__ inline bf16x8 cvt8(f32x4 a, f32x4 b) {
    bf16x8 r;
    r[0] = (__bf16)a[0]; r[1] = (__bf16)a[1]; r[2] = (__bf16)a[2]; r[3] = (__bf16)a[3];
    r[4] = (__bf16)b[0]; r[5] = (__bf16)b[1]; r[6] = (__bf16)b[2]; r[7] = (__bf16)b[3];
    return r;
}
__device__ inline float fast_tanh(float x) {
    x = fminf(9.f, fmaxf(-9.f, x));
    float t = __expf(2.f * x);
    return (t - 1.f) / (t + 1.f);
}

// ---------------- 1. h = X @ W^T + b : [M x 768] x [256 x 768]^T -> bf16 [M,256] ----
// BM=64 BN=128 BK=32, 256 thr = 4 waves in 2x2; wave computes 32x64 (2x4 MFMA frags).
#define SA 40
__global__ __launch_bounds__(256) void gemm_h(const float* __restrict__ X,
                                              const float* __restrict__ W,
                                              const float* __restrict__ bias,
                                              u16* __restrict__ H, int M) {
    __shared__ u16 As[64 * SA];
    __shared__ u16 Bs[128 * SA];
    int bm = blockIdx.x >> 1, bn = blockIdx.x & 1;
    int tid = threadIdx.x;
    int w = tid >> 6, lane = tid & 63;
    int wm = w & 1, wn = w >> 1;
    int row16 = lane & 15, quad = lane >> 4;

    int ar = bm * 64 + (tid >> 2); if (ar > M - 1) ar = M - 1;
    const float* ag = X + (size_t)ar * 768 + (tid & 3) * 8;
    u16* asw = As + (tid >> 2) * SA + (tid & 3) * 8;
    const float* bg0 = W + (size_t)(bn * 128 + (tid >> 2)) * 768 + (tid & 3) * 8;
    u16* bsw0 = Bs + (tid >> 2) * SA + (tid & 3) * 8;
    int j1 = tid + 256;
    const float* bg1 = W + (size_t)(bn * 128 + (j1 >> 2)) * 768 + (j1 & 3) * 8;
    u16* bsw1 = Bs + (j1 >> 2) * SA + (j1 & 3) * 8;

    const u16* ard0 = As + (wm * 32 + row16) * SA + quad * 8;
    const u16* ard1 = As + (wm * 32 + 16 + row16) * SA + quad * 8;
    const u16* brd = Bs + (wn * 64 + row16) * SA + quad * 8;

    f32x4 acc[2][4] = {};
    for (int k = 0; k < 768; k += 32) {
        bf16x8 va  = cvt8(*(const f32x4*)(ag + k),  *(const f32x4*)(ag + k + 4));
        bf16x8 vb0 = cvt8(*(const f32x4*)(bg0 + k), *(const f32x4*)(bg0 + k + 4));
        bf16x8 vb1 = cvt8(*(const f32x4*)(bg1 + k), *(const f32x4*)(bg1 + k + 4));
        __syncthreads();
        *(bf16x8*)asw = va;
        *(bf16x8*)bsw0 = vb0;
        *(bf16x8*)bsw1 = vb1;
        __syncthreads();
        bf16x8 af0 = *(const bf16x8*)ard0;
        bf16x8 af1 = *(const bf16x8*)ard1;
#pragma unroll
        for (int ni = 0; ni < 4; ++ni) {
            bf16x8 bf = *(const bf16x8*)(brd + ni * 16 * SA);
            acc[0][ni] = __builtin_amdgcn_mfma_f32_16x16x32_bf16(af0, bf, acc[0][ni], 0, 0, 0);
            acc[1][ni] = __builtin_amdgcn_mfma_f32_16x16x32_bf16(af1, bf, acc[1][ni], 0, 0, 0);
        }
    }
#pragma unroll
    for (int ni = 0; ni < 4; ++ni) {
        int gcol = bn * 128 + wn * 64 + ni * 16 + row16;
        float bv = bias[gcol];
#pragma unroll
        for (int mi = 0; mi < 2; ++mi) {
#pragma unroll
            for (int r = 0; r < 4; ++r) {
                int grow = bm * 64 + wm * 32 + mi * 16 + quad * 4 + r;
                if (grow < M) H[(size_t)grow * 256 + gcol] = f2bf(acc[mi][ni][r] + bv);
            }
        }
    }
}

// ---------------- 2. per-(node,head) attention scores (h bf16) ----------------------
__global__ __launch_bounds__(256) void node_scores(const u16* __restrict__ ha, const u16* __restrict__ hd,
                                                   const float* __restrict__ w_ads, const float* __restrict__ w_add,
                                                   const float* __restrict__ w_dds, const float* __restrict__ w_ddd,
                                                   float* __restrict__ as_ad, float* __restrict__ ad_ad,
                                                   float* __restrict__ as_dd, float* __restrict__ ad_dd, int N) {
    int gid = blockIdx.x * 256 + threadIdx.x;
    int n = gid >> 6;
    if (n >= N) return;
    int lane = gid & 63;
    int f = lane * 4;
    ushort4 av = *(const ushort4*)(ha + (size_t)n * 256 + f);
    ushort4 dv = *(const ushort4*)(hd + (size_t)n * 256 + f);
    float4 w1 = *(const float4*)(w_ads + f);
    float4 w2 = *(const float4*)(w_add + f);
    float4 w3 = *(const float4*)(w_dds + f);
    float4 w4 = *(const float4*)(w_ddd + f);
    float a0 = bf2f(av.x), a1 = bf2f(av.y), a2 = bf2f(av.z), a3 = bf2f(av.w);
    float d0 = bf2f(dv.x), d1 = bf2f(dv.y), d2 = bf2f(dv.z), d3 = bf2f(dv.w);
    float p1 = a0 * w1.x + a1 * w1.y + a2 * w1.z + a3 * w1.w;
    float p2 = d0 * w2.x + d1 * w2.y + d2 * w2.z + d3 * w2.w;
    float p3 = d0 * w3.x + d1 * w3.y + d2 * w3.z + d3 * w3.w;
    float p4 = d0 * w4.x + d1 * w4.y + d2 * w4.z + d3 * w4.w;
#pragma unroll
    for (int off = 16; off >= 1; off >>= 1) {
        p1 += __shfl_down(p1, off, 32);
        p2 += __shfl_down(p2, off, 32);
        p3 += __shfl_down(p3, off, 32);
        p4 += __shfl_down(p4, off, 32);
    }
    if ((lane & 31) == 0) {
        int h = lane >> 5;
        as_ad[n * 2 + h] = p1;
        ad_ad[n * 2 + h] = p2;
        as_dd[n * 2 + h] = p3;
        ad_dd[n * 2 + h] = p4;
    }
}

// ---------------- 3a. degree histogram ----------------------------------------------
__global__ __launch_bounds__(256) void count_edges(const int* __restrict__ ei, int* __restrict__ cnt, int E) {
    int e = blockIdx.x * 256 + threadIdx.x;
    if (e >= E) return;
    atomicAdd(&cnt[ei[E + e]], 1);
}

// ---------------- 3b. exclusive scan of two count arrays ----------------------------
__global__ __launch_bounds__(1024) void scan_two(const int* __restrict__ cntA, int* __restrict__ offA,
                                                 const int* __restrict__ cntB, int* __restrict__ offB, int n) {
    const int* cnt = blockIdx.x ? cntB : cntA;
    int* off = blockIdx.x ? offB : offA;
    __shared__ int smem[1024];
    __shared__ int carry_s;
    int tid = threadIdx.x;
    if (tid == 0) carry_s = 0;
    __syncthreads();
    for (int base = 0; base < n; base += 1024) {
        int i = base + tid;
        int v = (i < n) ? cnt[i] : 0;
        smem[tid] = v;
        __syncthreads();
#pragma unroll
        for (int d = 1; d < 1024; d <<= 1) {
            int t = (tid >= d) ? smem[tid - d] : 0;
            __syncthreads();
            smem[tid] += t;
            __syncthreads();
        }
        int incl = smem[tid];
        int carry = carry_s;
        if (i < n) off[i] = carry + incl - v;   // exclusive
        __syncthreads();
        if (tid == 1023) carry_s = carry + smem[1023];
        __syncthreads();
    }
    if (tid == 0) off[n] = carry_s;
}

// ---------------- 3c. fill CSR src lists --------------------------------------------
__global__ __launch_bounds__(256) void fill_csr(const int* __restrict__ ei, const int* __restrict__ off,
                                                int* __restrict__ cursor, int* __restrict__ srcs, int E) {
    int e = blockIdx.x * 256 + threadIdx.x;
    if (e >= E) return;
    int s = ei[e], d = ei[E + e];
    int slot = off[d] + atomicAdd(&cursor[d], 1);
    srcs[slot] = s;
}

// ---------------- 4. gather: one wave per dst node (h bf16) -------------------------
__global__ __launch_bounds__(256) void edge_gather(const int* __restrict__ off,
                                                   const int* __restrict__ srcs,
                                                   const float* __restrict__ a_src,
                                                   const float* __restrict__ a_dst,
                                                   const u16* __restrict__ h,
                                                   float* __restrict__ out, int N) {
    int gid = blockIdx.x * 256 + threadIdx.x;
    int d = gid >> 6;
    if (d >= N) return;
    int lane = gid & 63;
    int hh = lane >> 5;
    int f = lane * 4;
    float ad0 = a_dst[d * 2 + hh];
    int beg = off[d], end = off[d + 1];
    float4 acc = {0.f, 0.f, 0.f, 0.f};
    float S = 0.f;
    for (int p = beg; p < end; ++p) {
        int s = srcs[p];
        float v = a_src[s * 2 + hh] + ad0;
        v = v > 0.f ? v : 0.2f * v;           // leaky_relu(0.2)
        float ex = __expf(v);
        S += ex;
        ushort4 xv = *(const ushort4*)(h + (size_t)s * 256 + f);
        acc.x += ex * bf2f(xv.x);
        acc.y += ex * bf2f(xv.y);
        acc.z += ex * bf2f(xv.z);
        acc.w += ex * bf2f(xv.w);
    }
    float inv = 1.f / (S + 1e-16f);
    float4 o = {acc.x * inv, acc.y * inv, acc.z * inv, acc.w * inv};
    *(float4*)(out + (size_t)d * 256 + f) = o;
}

// ---------------- 5. semantic score -------------------------------------------------
// score[slot] += sum_{n,j} q[j] * tanh((relu(out) @ kW.T + kb)[n,j])
// 256 blocks = 128 m-groups x 2 col-halves; kW half (128 rows) in LDS bf16.
#define SK 264
__global__ __launch_bounds__(256) void kgemm_score(const float* __restrict__ outm,
                                                   const float* __restrict__ kW,
                                                   const float* __restrict__ kb,
                                                   const float* __restrict__ qv,
                                                   float* __restrict__ score, int slot) {
    __shared__ u16 Bs[128 * SK];          // 66 KB
    __shared__ float red[4];
    int bn = blockIdx.x & 1;              // which 128 output-cols
    int bidx = blockIdx.x >> 1;           // m-group 0..127
    int tid = threadIdx.x;
    int w = tid >> 6, lane = tid & 63;
    int row16 = lane & 15, quad = lane >> 4;

    // ---- stage kW[bn*128 .. +128) rows as bf16 into LDS (once per block) ----
#pragma unroll
    for (int i = 0; i < 16; ++i) {
        int c = tid + 256 * i;            // 4096 chunks of 8 elems
        int r = c >> 5, col8 = (c & 31) * 8;
        const float* src = kW + (size_t)(bn * 128 + r) * 256 + col8;
        *(bf16x8*)(Bs + r * SK + col8) = cvt8(*(const f32x4*)src, *(const f32x4*)(src + 4));
    }
    __syncthreads();

    // wave w handles 32 cols: n = bn*128 + w*32 + t*16 + row16, t in {0,1}
    float kb0 = kb[bn * 128 + w * 32 + row16];
    float qn0 = qv[bn * 128 + w * 32 + row16];
    float kb1 = kb[bn * 128 + w * 32 + 16 + row16];
    float qn1 = qv[bn * 128 + w * 32 + 16 + row16];
    const u16* b0 = Bs + (w * 32 + row16) * SK + quad * 8;
    const u16* b1 = Bs + (w * 32 + 16 + row16) * SK + quad * 8;

    float p = 0.f;
    for (int mt = bidx; mt < 1250; mt += 128) {
        const float* arow = outm + (size_t)(mt * 16 + row16) * 256 + quad * 8;
        // issue all 16 A loads up front (independent -> one latency round-trip)
        f32x4 a0[8], a1[8];
#pragma unroll
        for (int s = 0; s < 8; ++s) {
            a0[s] = *(const f32x4*)(arow + s * 32);
            a1[s] = *(const f32x4*)(arow + s * 32 + 4);
        }
        f32x4 acc0 = {0.f,0.f,0.f,0.f}, acc1 = {0.f,0.f,0.f,0.f};
#pragma unroll
        for (int s = 0; s < 8; ++s) {
            f32x4 x0 = a0[s], x1 = a1[s];
#pragma unroll
            for (int j = 0; j < 4; ++j) {   // relu
                x0[j] = x0[j] > 0.f ? x0[j] : 0.f;
                x1[j] = x1[j] > 0.f ? x1[j] : 0.f;
            }
            bf16x8 af = cvt8(x0, x1);
            bf16x8 bf0 = *(const bf16x8*)(b0 + s * 32);
            bf16x8 bf1 = *(const bf16x8*)(b1 + s * 32);
            acc0 = __builtin_amdgcn_mfma_f32_16x16x32_bf16(af, bf0, acc0, 0, 0, 0);
            acc1 = __builtin_amdgcn_mfma_f32_16x16x32_bf16(af, bf1, acc1, 0, 0, 0);
        }
#pragma unroll
        for (int r = 0; r < 4; ++r) {
            p += qn0 * fast_tanh(acc0[r] + kb0);
            p += qn1 * fast_tanh(acc1[r] + kb1);
        }
    }
#pragma unroll
    for (int off = 32; off >= 1; off >>= 1) p += __shfl_down(p, off, 64);
    if (lane == 0) red[w] = p;
    __syncthreads();
    if (tid == 0) unsafeAtomicAdd(&score[slot], red[0] + red[1] + red[2] + red[3]);
}

// ---------------- 6. softmax over 2 metapath scores, blend, gather del_idx ----------
__global__ __launch_bounds__(256) void final_combine(const float* __restrict__ out_ad,
                                                     const float* __restrict__ out_dd,
                                                     const float* __restrict__ score,
                                                     const int* __restrict__ del_idx,
                                                     float* __restrict__ out) {
    int i = blockIdx.x;
    int f = threadIdx.x;
    int node = del_idx[i];
    float s0 = score[0] * (1.f / 20000.f);
    float s1 = score[1] * (1.f / 20000.f);
    float m = fmaxf(s0, s1);
    float e0 = __expf(s0 - m), e1 = __expf(s1 - m);
    float inv = 1.f / (e0 + e1);
    float a0 = e0 * inv, a1 = e1 * inv;
    float v0 = out_ad[(size_t)node * 256 + f]; v0 = v0 > 0.f ? v0 : 0.f;
    float v1 = out_dd[(size_t)node * 256 + f]; v1 = v1 > 0.f ? v1 : 0.f;
    out[(size_t)i * 256 + f] = a0 * v0 + a1 * v1;
}

extern "C" void kernel_launch(void* const* d_in, const int* in_sizes, int n_in,
                              void* d_out, int out_size, void* d_ws, size_t ws_size,
                              hipStream_t stream) {
    const float* x_add    = (const float*)d_in[0];
    const float* x_del    = (const float*)d_in[1];
    const float* W_add    = (const float*)d_in[2];
    const float* b_add    = (const float*)d_in[3];
    const float* W_del    = (const float*)d_in[4];
    const float* b_del    = (const float*)d_in[5];
    const float* att_ad_s = (const float*)d_in[6];
    const float* att_ad_d = (const float*)d_in[7];
    const float* att_dd_s = (const float*)d_in[12];
    const float* att_dd_d = (const float*)d_in[13];
    const float* k_W      = (const float*)d_in[14];
    const float* k_b      = (const float*)d_in[15];
    const float* q        = (const float*)d_in[16];
    const int* ei_ad      = (const int*)d_in[17];
    const int* ei_dd      = (const int*)d_in[20];
    const int* del_idx    = (const int*)d_in[21];
    float* out = (float*)d_out;

    const int N = 20000, E = 200000;
    char* ws = (char*)d_ws;
    size_t o = 0;
    // ---- zeroed region ----
    int* cnt_ad = (int*)(ws + o); o += (size_t)N * 4;
    int* cur_ad = (int*)(ws + o); o += (size_t)N * 4;
    int* cnt_dd = (int*)(ws + o); o += (size_t)N * 4;
    int* cur_dd = (int*)(ws + o); o += (size_t)N * 4;
    float* score = (float*)(ws + o); o += 256;
    size_t zero_bytes = o;
    // ---- written-once region ----
    int* off_ad = (int*)(ws + o); o += (size_t)(N + 1) * 4;
    int* off_dd = (int*)(ws + o); o += (size_t)(N + 1) * 4;
    int* srcs_ad = (int*)(ws + o); o += (size_t)E * 4;
    int* srcs_dd = (int*)(ws + o); o += (size_t)E * 4;
    float* out_ad = (float*)(ws + o); o += (size_t)N * 256 * 4;
    float* out_dd = (float*)(ws + o); o += (size_t)N * 256 * 4;
    u16* ha    = (u16*)(ws + o); o += (size_t)N * 256 * 2;
    u16* hd    = (u16*)(ws + o); o += (size_t)N * 256 * 2;
    float* as_ad = (float*)(ws + o); o += (size_t)N * 2 * 4;
    float* ad_ad = (float*)(ws + o); o += (size_t)N * 2 * 4;
    float* as_dd = (float*)(ws + o); o += (size_t)N * 2 * 4;
    float* ad_dd = (float*)(ws + o); o += (size_t)N * 2 * 4;

    hipMemsetAsync(d_ws, 0, zero_bytes, stream);

    // CSR build
    count_edges<<<(E + 255) / 256, 256, 0, stream>>>(ei_ad, cnt_ad, E);
    count_edges<<<(E + 255) / 256, 256, 0, stream>>>(ei_dd, cnt_dd, E);
    scan_two<<<2, 1024, 0, stream>>>(cnt_ad, off_ad, cnt_dd, off_dd, N);
    fill_csr<<<(E + 255) / 256, 256, 0, stream>>>(ei_ad, off_ad, cur_ad, srcs_ad, E);
    fill_csr<<<(E + 255) / 256, 256, 0, stream>>>(ei_dd, off_dd, cur_dd, srcs_dd, E);

    gemm_h<<<626, 256, 0, stream>>>(x_add, W_add, b_add, ha, N);
    gemm_h<<<626, 256, 0, stream>>>(x_del, W_del, b_del, hd, N);
    node_scores<<<5000, 256, 0, stream>>>(ha, hd, att_ad_s, att_ad_d, att_dd_s, att_dd_d,
                                          as_ad, ad_ad, as_dd, ad_dd, N);

    edge_gather<<<5000, 256, 0, stream>>>(off_ad, srcs_ad, as_ad, ad_ad, ha, out_ad, N);
    edge_gather<<<5000, 256, 0, stream>>>(off_dd, srcs_dd, as_dd, ad_dd, hd, out_dd, N);

    kgemm_score<<<256, 256, 0, stream>>>(out_ad, k_W, k_b, q, score, 0);
    kgemm_score<<<256, 256, 0, stream>>>(out_dd, k_W, k_b, q, score, 1);
    final_combine<<<4096, 256, 0, stream>>>(out_ad, out_dd, score, del_idx, out);
}

// Round 6
// 415.427 us; speedup vs baseline: 4.6087x; 1.0809x over previous
//
#include <hip/hip_runtime.h>
#include <hip/hip_bf16.h>

// HAN forward, del-branch only (add-branch _group output is unused in the reference).
// Inputs f32 / int32; output f32 [4096,256]. h stored bf16.
//
// R6 changes:
//  - gemm_h: BM=128 BN=128 BK=32 (m97 proportions) -> 16 MFMA : 8 ds_read_b128 per
//    wave-kstep (was 8:6), both projections fused into ONE 628-block dispatch.
//  - dispatch fusion: count_edges, fill_csr, edge_gather, kgemm_score pairs each
//    merged into single launches (19 -> 9 dispatches).

typedef unsigned short u16;
typedef __attribute__((ext_vector_type(8))) __bf16 bf16x8;
typedef __attribute__((ext_vector_type(4))) float f32x4;

__device__ inline float bf2f(u16 u) {
    union { unsigned int i; float f; } c; c.i = ((unsigned int)u) << 16; return c.f;
}
__device__ inline u16 f2bf(float f) {  // round-to-nearest-even
    union { float f; unsigned int i; } c; c.f = f;
    return (u16)((c.i + 0x7fffu + ((c.i >> 16) & 1u)) >> 16);
}
__device__ inline bf16x8 cvt8(f32x4 a, f32x4 b) {
    bf16x8 r;
    r[0] = (__bf16)a[0]; r[1] = (__bf16)a[1]; r[2] = (__bf16)a[2]; r[3] = (__bf16)a[3];
    r[4] = (__bf16)b[0]; r[5] = (__bf16)b[1]; r[6] = (__bf16)b[2]; r[7] = (__bf16)b[3];
    return r;
}
__device__ inline float fast_tanh(float x) {
    x = fminf(9.f, fmaxf(-9.f, x));
    float t = __expf(2.f * x);
    return (t - 1.f) / (t + 1.f);
}

// ---------------- 1. h = X @ W^T + b, both node types in one dispatch --------------
// BM=128 BN=128 BK=32; 4 waves in 2x2, each wave 64x64 = 4x4 16x16x32 MFMA frags.
// LDS rows padded to 40 u16 (80 B): read/write groups (5r+q) mod 8 fully spread.
#define SA 40
#define MTILES 157                       // ceil(20000/128)
__global__ __launch_bounds__(256) void gemm_h2(const float* __restrict__ X0, const float* __restrict__ W0,
                                               const float* __restrict__ b0, u16* __restrict__ H0,
                                               const float* __restrict__ X1, const float* __restrict__ W1,
                                               const float* __restrict__ b1, u16* __restrict__ H1, int M) {
    __shared__ u16 As[128 * SA];
    __shared__ u16 Bs[128 * SA];
    int id = blockIdx.x;
    int which = id >= MTILES * 2;
    if (which) id -= MTILES * 2;
    int bm = id >> 1, bn = id & 1;
    const float* X = which ? X1 : X0;
    const float* W = which ? W1 : W0;
    const float* bias = which ? b1 : b0;
    u16* H = which ? H1 : H0;

    int tid = threadIdx.x;
    int w = tid >> 6, lane = tid & 63;
    int wm = w & 1, wn = w >> 1;
    int row16 = lane & 15, quad = lane >> 4;

    // staging: 512 chunks of 8 f32 per tile; thread handles chunks tid and tid+256
    int r0 = tid >> 2, r1 = (tid + 256) >> 2, cc = (tid & 3) * 8;
    int ar0 = bm * 128 + r0; if (ar0 > M - 1) ar0 = M - 1;
    int ar1 = bm * 128 + r1; if (ar1 > M - 1) ar1 = M - 1;
    const float* ag0 = X + (size_t)ar0 * 768 + cc;
    const float* ag1 = X + (size_t)ar1 * 768 + cc;
    const float* bg0 = W + (size_t)(bn * 128 + r0) * 768 + cc;
    const float* bg1 = W + (size_t)(bn * 128 + r1) * 768 + cc;
    u16* asw0 = As + r0 * SA + cc;
    u16* asw1 = As + r1 * SA + cc;
    u16* bsw0 = Bs + r0 * SA + cc;
    u16* bsw1 = Bs + r1 * SA + cc;

    const u16* ard = As + (wm * 64 + row16) * SA + quad * 8;
    const u16* brd = Bs + (wn * 64 + row16) * SA + quad * 8;

    f32x4 acc[4][4] = {};
    for (int k = 0; k < 768; k += 32) {
        bf16x8 va0 = cvt8(*(const f32x4*)(ag0 + k), *(const f32x4*)(ag0 + k + 4));
        bf16x8 va1 = cvt8(*(const f32x4*)(ag1 + k), *(const f32x4*)(ag1 + k + 4));
        bf16x8 vb0 = cvt8(*(const f32x4*)(bg0 + k), *(const f32x4*)(bg0 + k + 4));
        bf16x8 vb1 = cvt8(*(const f32x4*)(bg1 + k), *(const f32x4*)(bg1 + k + 4));
        __syncthreads();
        *(bf16x8*)asw0 = va0;
        *(bf16x8*)asw1 = va1;
        *(bf16x8*)bsw0 = vb0;
        *(bf16x8*)bsw1 = vb1;
        __syncthreads();
        bf16x8 af[4], bv[4];
#pragma unroll
        for (int i = 0; i < 4; ++i) {
            af[i] = *(const bf16x8*)(ard + i * 16 * SA);
            bv[i] = *(const bf16x8*)(brd + i * 16 * SA);
        }
#pragma unroll
        for (int mi = 0; mi < 4; ++mi)
#pragma unroll
            for (int ni = 0; ni < 4; ++ni)
                acc[mi][ni] = __builtin_amdgcn_mfma_f32_16x16x32_bf16(af[mi], bv[ni], acc[mi][ni], 0, 0, 0);
    }
#pragma unroll
    for (int ni = 0; ni < 4; ++ni) {
        int gcol = bn * 128 + wn * 64 + ni * 16 + row16;
        float bvv = bias[gcol];
#pragma unroll
        for (int mi = 0; mi < 4; ++mi) {
#pragma unroll
            for (int r = 0; r < 4; ++r) {
                int grow = bm * 128 + wm * 64 + mi * 16 + quad * 4 + r;
                if (grow < M) H[(size_t)grow * 256 + gcol] = f2bf(acc[mi][ni][r] + bvv);
            }
        }
    }
}

// ---------------- 2. per-(node,head) attention scores (h bf16) ----------------------
__global__ __launch_bounds__(256) void node_scores(const u16* __restrict__ ha, const u16* __restrict__ hd,
                                                   const float* __restrict__ w_ads, const float* __restrict__ w_add,
                                                   const float* __restrict__ w_dds, const float* __restrict__ w_ddd,
                                                   float* __restrict__ as_ad, float* __restrict__ ad_ad,
                                                   float* __restrict__ as_dd, float* __restrict__ ad_dd, int N) {
    int gid = blockIdx.x * 256 + threadIdx.x;
    int n = gid >> 6;
    if (n >= N) return;
    int lane = gid & 63;
    int f = lane * 4;
    ushort4 av = *(const ushort4*)(ha + (size_t)n * 256 + f);
    ushort4 dv = *(const ushort4*)(hd + (size_t)n * 256 + f);
    float4 w1 = *(const float4*)(w_ads + f);
    float4 w2 = *(const float4*)(w_add + f);
    float4 w3 = *(const float4*)(w_dds + f);
    float4 w4 = *(const float4*)(w_ddd + f);
    float a0 = bf2f(av.x), a1 = bf2f(av.y), a2 = bf2f(av.z), a3 = bf2f(av.w);
    float d0 = bf2f(dv.x), d1 = bf2f(dv.y), d2 = bf2f(dv.z), d3 = bf2f(dv.w);
    float p1 = a0 * w1.x + a1 * w1.y + a2 * w1.z + a3 * w1.w;
    float p2 = d0 * w2.x + d1 * w2.y + d2 * w2.z + d3 * w2.w;
    float p3 = d0 * w3.x + d1 * w3.y + d2 * w3.z + d3 * w3.w;
    float p4 = d0 * w4.x + d1 * w4.y + d2 * w4.z + d3 * w4.w;
#pragma unroll
    for (int off = 16; off >= 1; off >>= 1) {
        p1 += __shfl_down(p1, off, 32);
        p2 += __shfl_down(p2, off, 32);
        p3 += __shfl_down(p3, off, 32);
        p4 += __shfl_down(p4, off, 32);
    }
    if ((lane & 31) == 0) {
        int h = lane >> 5;
        as_ad[n * 2 + h] = p1;
        ad_ad[n * 2 + h] = p2;
        as_dd[n * 2 + h] = p3;
        ad_dd[n * 2 + h] = p4;
    }
}

// ---------------- 3a. degree histogram, both edge sets ------------------------------
__global__ __launch_bounds__(256) void count_edges2(const int* __restrict__ eiA, int* __restrict__ cntA,
                                                    const int* __restrict__ eiB, int* __restrict__ cntB, int E) {
    int idx = blockIdx.x * 256 + threadIdx.x;
    int which = idx >= E;
    int e = idx - (which ? E : 0);
    if (e >= E) return;
    const int* ei = which ? eiB : eiA;
    int* cnt = which ? cntB : cntA;
    atomicAdd(&cnt[ei[E + e]], 1);
}

// ---------------- 3b. exclusive scan of two count arrays ----------------------------
__global__ __launch_bounds__(1024) void scan_two(const int* __restrict__ cntA, int* __restrict__ offA,
                                                 const int* __restrict__ cntB, int* __restrict__ offB, int n) {
    const int* cnt = blockIdx.x ? cntB : cntA;
    int* off = blockIdx.x ? offB : offA;
    __shared__ int smem[1024];
    __shared__ int carry_s;
    int tid = threadIdx.x;
    if (tid == 0) carry_s = 0;
    __syncthreads();
    for (int base = 0; base < n; base += 1024) {
        int i = base + tid;
        int v = (i < n) ? cnt[i] : 0;
        smem[tid] = v;
        __syncthreads();
#pragma unroll
        for (int d = 1; d < 1024; d <<= 1) {
            int t = (tid >= d) ? smem[tid - d] : 0;
            __syncthreads();
            smem[tid] += t;
            __syncthreads();
        }
        int incl = smem[tid];
        int carry = carry_s;
        if (i < n) off[i] = carry + incl - v;   // exclusive
        __syncthreads();
        if (tid == 1023) carry_s = carry + smem[1023];
        __syncthreads();
    }
    if (tid == 0) off[n] = carry_s;
}

// ---------------- 3c. fill CSR src lists, both edge sets ----------------------------
__global__ __launch_bounds__(256) void fill_csr2(const int* __restrict__ eiA, const int* __restrict__ offA,
                                                 int* __restrict__ curA, int* __restrict__ srcsA,
                                                 const int* __restrict__ eiB, const int* __restrict__ offB,
                                                 int* __restrict__ curB, int* __restrict__ srcsB, int E) {
    int idx = blockIdx.x * 256 + threadIdx.x;
    int which = idx >= E;
    int e = idx - (which ? E : 0);
    if (e >= E) return;
    const int* ei = which ? eiB : eiA;
    const int* off = which ? offB : offA;
    int* cursor = which ? curB : curA;
    int* srcs = which ? srcsB : srcsA;
    int s = ei[e], d = ei[E + e];
    int slot = off[d] + atomicAdd(&cursor[d], 1);
    srcs[slot] = s;
}

// ---------------- 4. gather: one wave per dst node, both metapaths ------------------
__global__ __launch_bounds__(256) void edge_gather2(const int* __restrict__ offA, const int* __restrict__ srcsA,
                                                    const float* __restrict__ asA, const float* __restrict__ adA,
                                                    const u16* __restrict__ hA, float* __restrict__ outA,
                                                    const int* __restrict__ offB, const int* __restrict__ srcsB,
                                                    const float* __restrict__ asB, const float* __restrict__ adB,
                                                    const u16* __restrict__ hB, float* __restrict__ outB, int N) {
    int gid = blockIdx.x * 256 + threadIdx.x;
    int dall = gid >> 6;
    int which = dall >= N;
    int d = dall - (which ? N : 0);
    if (d >= N) return;
    const int* off = which ? offB : offA;
    const int* srcs = which ? srcsB : srcsA;
    const float* a_src = which ? asB : asA;
    const float* a_dst = which ? adB : adA;
    const u16* h = which ? hB : hA;
    float* out = which ? outB : outA;
    int lane = gid & 63;
    int hh = lane >> 5;
    int f = lane * 4;
    float ad0 = a_dst[d * 2 + hh];
    int beg = off[d], end = off[d + 1];
    float4 acc = {0.f, 0.f, 0.f, 0.f};
    float S = 0.f;
    for (int p = beg; p < end; ++p) {
        int s = srcs[p];
        float v = a_src[s * 2 + hh] + ad0;
        v = v > 0.f ? v : 0.2f * v;           // leaky_relu(0.2)
        float ex = __expf(v);
        S += ex;
        ushort4 xv = *(const ushort4*)(h + (size_t)s * 256 + f);
        acc.x += ex * bf2f(xv.x);
        acc.y += ex * bf2f(xv.y);
        acc.z += ex * bf2f(xv.z);
        acc.w += ex * bf2f(xv.w);
    }
    float inv = 1.f / (S + 1e-16f);
    float4 o = {acc.x * inv, acc.y * inv, acc.z * inv, acc.w * inv};
    *(float4*)(out + (size_t)d * 256 + f) = o;
}

// ---------------- 5. semantic scores, both metapaths in one dispatch ----------------
// score[slot] += sum_{n,j} q[j] * tanh((relu(out) @ kW.T + kb)[n,j])
#define SK 264
__global__ __launch_bounds__(256) void kgemm_score2(const float* __restrict__ outA,
                                                    const float* __restrict__ outB,
                                                    const float* __restrict__ kW,
                                                    const float* __restrict__ kb,
                                                    const float* __restrict__ qv,
                                                    float* __restrict__ score) {
    __shared__ u16 Bs[128 * SK];          // 66 KB
    __shared__ float red[4];
    int slot = blockIdx.x >> 8;           // 0..1
    int b = blockIdx.x & 255;
    const float* outm = slot ? outB : outA;
    int bn = b & 1;
    int bidx = b >> 1;                    // 0..127
    int tid = threadIdx.x;
    int w = tid >> 6, lane = tid & 63;
    int row16 = lane & 15, quad = lane >> 4;

#pragma unroll
    for (int i = 0; i < 16; ++i) {
        int c = tid + 256 * i;
        int r = c >> 5, col8 = (c & 31) * 8;
        const float* src = kW + (size_t)(bn * 128 + r) * 256 + col8;
        *(bf16x8*)(Bs + r * SK + col8) = cvt8(*(const f32x4*)src, *(const f32x4*)(src + 4));
    }
    __syncthreads();

    float kb0 = kb[bn * 128 + w * 32 + row16];
    float qn0 = qv[bn * 128 + w * 32 + row16];
    float kb1 = kb[bn * 128 + w * 32 + 16 + row16];
    float qn1 = qv[bn * 128 + w * 32 + 16 + row16];
    const u16* b0 = Bs + (w * 32 + row16) * SK + quad * 8;
    const u16* b1 = Bs + (w * 32 + 16 + row16) * SK + quad * 8;

    float p = 0.f;
    for (int mt = bidx; mt < 1250; mt += 128) {
        const float* arow = outm + (size_t)(mt * 16 + row16) * 256 + quad * 8;
        f32x4 a0[8], a1[8];
#pragma unroll
        for (int s = 0; s < 8; ++s) {
            a0[s] = *(const f32x4*)(arow + s * 32);
            a1[s] = *(const f32x4*)(arow + s * 32 + 4);
        }
        f32x4 acc0 = {0.f,0.f,0.f,0.f}, acc1 = {0.f,0.f,0.f,0.f};
#pragma unroll
        for (int s = 0; s < 8; ++s) {
            f32x4 x0 = a0[s], x1 = a1[s];
#pragma unroll
            for (int j = 0; j < 4; ++j) {
                x0[j] = x0[j] > 0.f ? x0[j] : 0.f;
                x1[j] = x1[j] > 0.f ? x1[j] : 0.f;
            }
            bf16x8 af = cvt8(x0, x1);
            bf16x8 bf0 = *(const bf16x8*)(b0 + s * 32);
            bf16x8 bf1 = *(const bf16x8*)(b1 + s * 32);
            acc0 = __builtin_amdgcn_mfma_f32_16x16x32_bf16(af, bf0, acc0, 0, 0, 0);
            acc1 = __builtin_amdgcn_mfma_f32_16x16x32_bf16(af, bf1, acc1, 0, 0, 0);
        }
#pragma unroll
        for (int r = 0; r < 4; ++r) {
            p += qn0 * fast_tanh(acc0[r] + kb0);
            p += qn1 * fast_tanh(acc1[r] + kb1);
        }
    }
#pragma unroll
    for (int off = 32; off >= 1; off >>= 1) p += __shfl_down(p, off, 64);
    if (lane == 0) red[w] = p;
    __syncthreads();
    if (tid == 0) unsafeAtomicAdd(&score[slot], red[0] + red[1] + red[2] + red[3]);
}

// ---------------- 6. softmax over 2 metapath scores, blend, gather del_idx ----------
__global__ __launch_bounds__(256) void final_combine(const float* __restrict__ out_ad,
                                                     const float* __restrict__ out_dd,
                                                     const float* __restrict__ score,
                                                     const int* __restrict__ del_idx,
                                                     float* __restrict__ out) {
    int i = blockIdx.x;
    int f = threadIdx.x;
    int node = del_idx[i];
    float s0 = score[0] * (1.f / 20000.f);
    float s1 = score[1] * (1.f / 20000.f);
    float m = fmaxf(s0, s1);
    float e0 = __expf(s0 - m), e1 = __expf(s1 - m);
    float inv = 1.f / (e0 + e1);
    float a0 = e0 * inv, a1 = e1 * inv;
    float v0 = out_ad[(size_t)node * 256 + f]; v0 = v0 > 0.f ? v0 : 0.f;
    float v1 = out_dd[(size_t)node * 256 + f]; v1 = v1 > 0.f ? v1 : 0.f;
    out[(size_t)i * 256 + f] = a0 * v0 + a1 * v1;
}

extern "C" void kernel_launch(void* const* d_in, const int* in_sizes, int n_in,
                              void* d_out, int out_size, void* d_ws, size_t ws_size,
                              hipStream_t stream) {
    const float* x_add    = (const float*)d_in[0];
    const float* x_del    = (const float*)d_in[1];
    const float* W_add    = (const float*)d_in[2];
    const float* b_add    = (const float*)d_in[3];
    const float* W_del    = (const float*)d_in[4];
    const float* b_del    = (const float*)d_in[5];
    const float* att_ad_s = (const float*)d_in[6];
    const float* att_ad_d = (const float*)d_in[7];
    const float* att_dd_s = (const float*)d_in[12];
    const float* att_dd_d = (const float*)d_in[13];
    const float* k_W      = (const float*)d_in[14];
    const float* k_b      = (const float*)d_in[15];
    const float* q        = (const float*)d_in[16];
    const int* ei_ad      = (const int*)d_in[17];
    const int* ei_dd      = (const int*)d_in[20];
    const int* del_idx    = (const int*)d_in[21];
    float* out = (float*)d_out;

    const int N = 20000, E = 200000;
    char* ws = (char*)d_ws;
    size_t o = 0;
    // ---- zeroed region ----
    int* cnt_ad = (int*)(ws + o); o += (size_t)N * 4;
    int* cur_ad = (int*)(ws + o); o += (size_t)N * 4;
    int* cnt_dd = (int*)(ws + o); o += (size_t)N * 4;
    int* cur_dd = (int*)(ws + o); o += (size_t)N * 4;
    float* score = (float*)(ws + o); o += 256;
    size_t zero_bytes = o;
    // ---- written-once region ----
    int* off_ad = (int*)(ws + o); o += (size_t)(N + 1) * 4;
    int* off_dd = (int*)(ws + o); o += (size_t)(N + 1) * 4;
    int* srcs_ad = (int*)(ws + o); o += (size_t)E * 4;
    int* srcs_dd = (int*)(ws + o); o += (size_t)E * 4;
    float* out_ad = (float*)(ws + o); o += (size_t)N * 256 * 4;
    float* out_dd = (float*)(ws + o); o += (size_t)N * 256 * 4;
    u16* ha    = (u16*)(ws + o); o += (size_t)N * 256 * 2;
    u16* hd    = (u16*)(ws + o); o += (size_t)N * 256 * 2;
    float* as_ad = (float*)(ws + o); o += (size_t)N * 2 * 4;
    float* ad_ad = (float*)(ws + o); o += (size_t)N * 2 * 4;
    float* as_dd = (float*)(ws + o); o += (size_t)N * 2 * 4;
    float* ad_dd = (float*)(ws + o); o += (size_t)N * 2 * 4;

    hipMemsetAsync(d_ws, 0, zero_bytes, stream);

    // CSR build (fused pairs)
    count_edges2<<<(2 * E + 255) / 256, 256, 0, stream>>>(ei_ad, cnt_ad, ei_dd, cnt_dd, E);
    scan_two<<<2, 1024, 0, stream>>>(cnt_ad, off_ad, cnt_dd, off_dd, N);
    fill_csr2<<<(2 * E + 255) / 256, 256, 0, stream>>>(ei_ad, off_ad, cur_ad, srcs_ad,
                                                       ei_dd, off_dd, cur_dd, srcs_dd, E);

    // both projections in one dispatch: 2 * (157 m-tiles * 2 n-tiles) = 628 blocks
    gemm_h2<<<4 * MTILES, 256, 0, stream>>>(x_add, W_add, b_add, ha,
                                            x_del, W_del, b_del, hd, N);
    node_scores<<<5000, 256, 0, stream>>>(ha, hd, att_ad_s, att_ad_d, att_dd_s, att_dd_d,
                                          as_ad, ad_ad, as_dd, ad_dd, N);

    edge_gather2<<<10000, 256, 0, stream>>>(off_ad, srcs_ad, as_ad, ad_ad, ha, out_ad,
                                            off_dd, srcs_dd, as_dd, ad_dd, hd, out_dd, N);

    kgemm_score2<<<512, 256, 0, stream>>>(out_ad, out_dd, k_W, k_b, q, score);
    final_combine<<<4096, 256, 0, stream>>>(out_ad, out_dd, score, del_idx, out);
}